// Round 6
// baseline (678.540 us; speedup 1.0000x reference)
//
#include <hip/hip_runtime.h>
#include <hip/hip_bf16.h>
#include <math.h>

// Problem constants
#define B_ 4
#define S_ 2048
#define D_ 1024
#define H_ 16
#define DH_ 64
#define INNER_ 1024   // H_*DH_
#define N3_ 3072      // 3*INNER_
#define ROWS_ 8192    // B_*S_

typedef __attribute__((ext_vector_type(8))) short short8;
typedef __attribute__((ext_vector_type(4))) float f32x4;

// ---------------------------------------------------------------------------
// split fp32 -> bf16 hi + bf16 lo (hi+lo reproduces ~16 mantissa bits)
// ---------------------------------------------------------------------------
__device__ __forceinline__ void split2(float x, ushort& hi, ushort& lo) {
    __hip_bfloat16 h = __float2bfloat16(x);
    float hf = __bfloat162float(h);
    __hip_bfloat16 l = __float2bfloat16(x - hf);
    hi = *reinterpret_cast<ushort*>(&h);
    lo = *reinterpret_cast<ushort*>(&l);
}

// XOR-swizzled byte offset into a row-major [.][64] bf16 tile (128B rows).
__device__ __forceinline__ int swz(int row, int colByte) {
    return row * 128 + (colByte ^ ((row & 7) << 4));
}

// ---------------------------------------------------------------------------
// LayerNorm: one block (256 threads) per row of 1024 floats.
// Emits pre-split bf16 hi/lo for the MFMA QKV GEMM.
// ---------------------------------------------------------------------------
__global__ __launch_bounds__(256) void ln_kernel(const float* __restrict__ x,
                                                 const float* __restrict__ gamma,
                                                 const float* __restrict__ beta,
                                                 ushort* __restrict__ xn_h,
                                                 ushort* __restrict__ xn_l) {
    const int row = blockIdx.x;
    const int tid = threadIdx.x;
    const float4 v = ((const float4*)(x + (size_t)row * D_))[tid];
    float s  = v.x + v.y + v.z + v.w;
    float ss = v.x * v.x + v.y * v.y + v.z * v.z + v.w * v.w;
    #pragma unroll
    for (int off = 32; off > 0; off >>= 1) {
        s  += __shfl_down(s, off);
        ss += __shfl_down(ss, off);
    }
    __shared__ float red[8];
    const int wave = tid >> 6, lane = tid & 63;
    if (lane == 0) { red[wave] = s; red[4 + wave] = ss; }
    __syncthreads();
    const float S  = red[0] + red[1] + red[2] + red[3];
    const float SS = red[4] + red[5] + red[6] + red[7];
    const float mu  = S * (1.0f / D_);
    const float var = SS * (1.0f / D_) - mu * mu;
    const float rs  = rsqrtf(var + 1e-5f);
    const float4 g  = ((const float4*)gamma)[tid];
    const float4 bb = ((const float4*)beta)[tid];
    float o0 = (v.x - mu) * rs * g.x + bb.x;
    float o1 = (v.y - mu) * rs * g.y + bb.y;
    float o2 = (v.z - mu) * rs * g.z + bb.z;
    float o3 = (v.w - mu) * rs * g.w + bb.w;
    ushort h0, l0, h1, l1, h2, l2, h3, l3;
    split2(o0, h0, l0); split2(o1, h1, l1);
    split2(o2, h2, l2); split2(o3, h3, l3);
    *(ushort4*)(xn_h + (size_t)row * D_ + tid * 4) = make_ushort4(h0, h1, h2, h3);
    *(ushort4*)(xn_l + (size_t)row * D_ + tid * 4) = make_ushort4(l0, l1, l2, l3);
}

// ---------------------------------------------------------------------------
// Weight transpose+split: W [K][N] fp32 -> Th/Tl [N][K] bf16.
// ---------------------------------------------------------------------------
__global__ __launch_bounds__(256) void wtrans_kernel(const float* __restrict__ W,
                                                     ushort* __restrict__ Th,
                                                     ushort* __restrict__ Tl,
                                                     int K, int N) {
    __shared__ float tile[64][68];
    const int tid = threadIdx.x;
    const int n0 = blockIdx.x * 64, k0 = blockIdx.y * 64;
    const int kr = tid >> 4, nc = (tid & 15) * 4;
    #pragma unroll
    for (int li = 0; li < 4; ++li) {
        const int k = kr + li * 16;
        *(float4*)&tile[k][nc] = *(const float4*)(W + (size_t)(k0 + k) * N + n0 + nc);
    }
    __syncthreads();
    const int nl = tid >> 2;
    const int ks = (tid & 3) * 16;
    ushort hbuf[16], lbuf[16];
    #pragma unroll
    for (int i = 0; i < 16; ++i) split2(tile[ks + i][nl], hbuf[i], lbuf[i]);
    ushort* th = Th + (size_t)(n0 + nl) * K + k0 + ks;
    ushort* tl = Tl + (size_t)(n0 + nl) * K + k0 + ks;
    #pragma unroll
    for (int i = 0; i < 4; ++i) {
        *(ushort4*)(th + i * 4) = make_ushort4(hbuf[i*4], hbuf[i*4+1], hbuf[i*4+2], hbuf[i*4+3]);
        *(ushort4*)(tl + i * 4) = make_ushort4(lbuf[i*4], lbuf[i*4+1], lbuf[i*4+2], lbuf[i*4+3]);
    }
}

// ---------------------------------------------------------------------------
// Split-bf16 MFMA GEMM: C[M,N] = (Ah+Al)[M,K] @ (Bh+Bl)^T[N,K]  (+ bias)
// ---------------------------------------------------------------------------
__global__ __launch_bounds__(256) void gemm_split_kernel(
        const ushort* __restrict__ Ah, const ushort* __restrict__ Al,
        const ushort* __restrict__ Bh, const ushort* __restrict__ Bl,
        float* __restrict__ C, int M, int N, int K,
        const float* __restrict__ bias) {
    __shared__ __align__(16) ushort As_h[128 * 64], As_l[128 * 64];
    __shared__ __align__(16) ushort Bs_h[128 * 64], Bs_l[128 * 64];
    const int tid  = threadIdx.x;
    const int lane = tid & 63;
    const int wv   = tid >> 6;
    const int lr = lane & 15, lg = lane >> 4;
    const int wr = wv >> 1, wc = wv & 1;
    const int m0 = blockIdx.y * 128, n0 = blockIdx.x * 128;

    f32x4 acc[4][4];
    #pragma unroll
    for (int i = 0; i < 4; ++i)
        #pragma unroll
        for (int j = 0; j < 4; ++j) acc[i][j] = (f32x4){0.f, 0.f, 0.f, 0.f};

    const int sr = tid >> 3;
    const int ss = (tid & 7) * 16;

    for (int k0 = 0; k0 < K; k0 += 64) {
        __syncthreads();
        #pragma unroll
        for (int li = 0; li < 4; ++li) {
            const int r = sr + li * 32;
            const size_t ga = (size_t)(m0 + r) * K + k0 + (ss >> 1);
            const size_t gb = (size_t)(n0 + r) * K + k0 + (ss >> 1);
            const int off = swz(r, ss);
            *(uint4*)((char*)As_h + off) = *(const uint4*)(Ah + ga);
            *(uint4*)((char*)As_l + off) = *(const uint4*)(Al + ga);
            *(uint4*)((char*)Bs_h + off) = *(const uint4*)(Bh + gb);
            *(uint4*)((char*)Bs_l + off) = *(const uint4*)(Bl + gb);
        }
        __syncthreads();
        #pragma unroll
        for (int kc = 0; kc < 2; ++kc) {
            const int cb = kc * 64 + lg * 16;
            short8 ah[4], al[4], bhf[4], blf[4];
            #pragma unroll
            for (int i = 0; i < 4; ++i) {
                const int ra = wr * 64 + i * 16 + lr;
                const int rb = wc * 64 + i * 16 + lr;
                ah[i]  = *(short8*)((char*)As_h + swz(ra, cb));
                al[i]  = *(short8*)((char*)As_l + swz(ra, cb));
                bhf[i] = *(short8*)((char*)Bs_h + swz(rb, cb));
                blf[i] = *(short8*)((char*)Bs_l + swz(rb, cb));
            }
            #pragma unroll
            for (int mi = 0; mi < 4; ++mi)
                #pragma unroll
                for (int ni = 0; ni < 4; ++ni) {
                    acc[mi][ni] = __builtin_amdgcn_mfma_f32_16x16x32_bf16(ah[mi], bhf[ni], acc[mi][ni], 0, 0, 0);
                    acc[mi][ni] = __builtin_amdgcn_mfma_f32_16x16x32_bf16(ah[mi], blf[ni], acc[mi][ni], 0, 0, 0);
                    acc[mi][ni] = __builtin_amdgcn_mfma_f32_16x16x32_bf16(al[mi], bhf[ni], acc[mi][ni], 0, 0, 0);
                }
        }
    }

    #pragma unroll
    for (int mi = 0; mi < 4; ++mi) {
        #pragma unroll
        for (int rr = 0; rr < 4; ++rr) {
            const int row = m0 + wr * 64 + mi * 16 + lg * 4 + rr;
            float* crow = C + (size_t)row * N + n0 + wc * 64;
            #pragma unroll
            for (int ni = 0; ni < 4; ++ni) {
                const int col = ni * 16 + lr;
                float v = acc[mi][ni][rr];
                if (bias) v += bias[n0 + wc * 64 + col];
                crow[col] = v;
            }
        }
    }
}

// ---------------------------------------------------------------------------
// RoPE cos/sin table: [S_][32] each.
// ---------------------------------------------------------------------------
__global__ __launch_bounds__(256) void rope_table_kernel(float* __restrict__ cost,
                                                         float* __restrict__ sint) {
    const int idx = blockIdx.x * 256 + threadIdx.x;
    const int s = idx >> 5;
    const int i = idx & 31;
    const float inv = powf(10000.0f, -(2.0f * (float)i) / 64.0f);
    const float f = (float)s * inv;
    float sv, cv;
    sincosf(f, &sv, &cv);
    cost[idx] = cv;
    sint[idx] = sv;
}

// ---------------------------------------------------------------------------
// RoPE + split, IN PLACE over the qkv fp32 buffer.  One block per row.
// Row segment layout after this kernel (ushort units, row base = row*6144):
//   [0,1024)    Qh   (rope'd, pre-scaled by 1/8)   [1024,2048) Ql
//   [2048,3072) Kh   (rope'd)                      [3072,4096) Kl
//   [4096,5120) Vh                                 [5120,6144) Vl
// Safe in-place: block loads its whole row to LDS, syncs, then overwrites.
// ---------------------------------------------------------------------------
__global__ __launch_bounds__(256) void rope_split_kernel(float* __restrict__ qkv,
                                                         const float* __restrict__ cost,
                                                         const float* __restrict__ sint) {
    __shared__ float qs[1024], ks[1024], vs[1024];
    __shared__ ushort qhs[1024], qls[1024], khs[1024], kls[1024], vhs[1024], vls[1024];
    const int row = blockIdx.x;
    const int spos = row & (S_ - 1);
    const int tid = threadIdx.x;
    float* base = qkv + (size_t)row * N3_;
    ((float4*)qs)[tid] = ((const float4*)(base))[tid];
    ((float4*)ks)[tid] = ((const float4*)(base + 1024))[tid];
    ((float4*)vs)[tid] = ((const float4*)(base + 2048))[tid];
    __syncthreads();
    #pragma unroll
    for (int pp = 0; pp < 2; ++pp) {
        const int p = tid + pp * 256;            // pair id 0..511
        const int h = p >> 5, d = p & 31;
        const float c  = cost[spos * 32 + d];
        const float sn = sint[spos * 32 + d];
        const int c1 = h * 64 + d, c2 = c1 + 32;
        const float q1 = qs[c1], q2 = qs[c2];
        const float k1 = ks[c1], k2 = ks[c2];
        ushort hh, ll;
        split2((q1 * c - q2 * sn) * 0.125f, hh, ll); qhs[c1] = hh; qls[c1] = ll;
        split2((q1 * sn + q2 * c) * 0.125f, hh, ll); qhs[c2] = hh; qls[c2] = ll;
        split2(k1 * c - k2 * sn, hh, ll);            khs[c1] = hh; kls[c1] = ll;
        split2(k1 * sn + k2 * c, hh, ll);            khs[c2] = hh; kls[c2] = ll;
        split2(vs[c1], hh, ll);                      vhs[c1] = hh; vls[c1] = ll;
        split2(vs[c2], hh, ll);                      vhs[c2] = hh; vls[c2] = ll;
    }
    __syncthreads();
    ushort* W = (ushort*)base;
    *(ushort4*)(W + tid * 4)        = *(ushort4*)(qhs + tid * 4);
    *(ushort4*)(W + 1024 + tid * 4) = *(ushort4*)(qls + tid * 4);
    *(ushort4*)(W + 2048 + tid * 4) = *(ushort4*)(khs + tid * 4);
    *(ushort4*)(W + 3072 + tid * 4) = *(ushort4*)(kls + tid * 4);
    *(ushort4*)(W + 4096 + tid * 4) = *(ushort4*)(vhs + tid * 4);
    *(ushort4*)(W + 5120 + tid * 4) = *(ushort4*)(vls + tid * 4);
}

// ---------------------------------------------------------------------------
// Flash attention v5: split-bf16 MFMA, staging from PRE-SPLIT qkv (no split2
// for K/V in the hot loop).  Structure otherwise as v4.
// ---------------------------------------------------------------------------
__global__ __launch_bounds__(256) void attn_mfma_kernel(const ushort* __restrict__ Q16,
                                                        ushort* __restrict__ att_h,
                                                        ushort* __restrict__ att_l) {
    __shared__ __align__(16) ushort sKh[64 * 64], sKl[64 * 64];
    __shared__ __align__(16) ushort sVh[64 * 64], sVl[64 * 64];
    __shared__ __align__(16) ushort Ph[4][16 * 64], Pl[4][16 * 64];

    const int tid  = threadIdx.x;
    const int lane = tid & 63;
    const int wv   = tid >> 6;
    const int lr   = lane & 15;
    const int lg   = lane >> 4;

    const int bh = blockIdx.x;
    const int b  = bh >> 4;
    const int h  = bh & 15;
    const int q0 = blockIdx.y * 64;

    // ---- Q fragments from pre-split/pre-scaled global
    const int qrow = q0 + wv * 16 + lr;
    const ushort* qp = Q16 + (size_t)(b * S_ + qrow) * 6144 + h * 64;
    short8 qh[2], ql[2];
    #pragma unroll
    for (int kc = 0; kc < 2; ++kc) {
        qh[kc] = *(const short8*)(qp + kc * 32 + lg * 8);
        ql[kc] = *(const short8*)(qp + 1024 + kc * 32 + lg * 8);
    }

    f32x4 accO[4];
    #pragma unroll
    for (int t = 0; t < 4; ++t) accO[t] = (f32x4){0.f, 0.f, 0.f, 0.f};
    float mrun[4] = {-1e30f, -1e30f, -1e30f, -1e30f};
    float lrun[4] = {0.f, 0.f, 0.f, 0.f};

    // staging indices
    const int vjp = tid & 31;          // V: j-pair 0..31
    const int vd  = (tid >> 5) * 8;    // V: d base 0..56

    for (int j0 = 0; j0 < S_; j0 += 64) {
        __syncthreads();

        // ---- stage K tile: rows j0..j0+63 of head h, 128B hi + 128B lo per row
        {
            const ushort* ktb = Q16 + (size_t)(b * S_ + j0) * 6144 + 2048 + h * 64;
            #pragma unroll
            for (int it = 0; it < 2; ++it) {
                const int c = tid + it * 256;      // chunk 0..511
                const int r = c >> 3, sl = c & 7;
                const int off = swz(r, sl * 16);
                const size_t g = (size_t)r * 6144 + sl * 8;
                *(uint4*)((char*)sKh + off) = *(const uint4*)(ktb + g);
                *(uint4*)((char*)sKl + off) = *(const uint4*)(ktb + g + 1024);
            }
        }
        // ---- stage V tile transposed: Vt[d][j].  Lanes: vjp spans 32 cols
        // (full 128B rows per instruction -> 2-way = free).
        {
            const ushort* vtb = Q16 + (size_t)(b * S_ + j0) * 6144 + 4096 + h * 64;
            ushort a0[8], a1[8], b0[8], b1[8];
            *(uint4*)a0 = *(const uint4*)(vtb + (size_t)(2 * vjp) * 6144 + vd);
            *(uint4*)a1 = *(const uint4*)(vtb + (size_t)(2 * vjp + 1) * 6144 + vd);
            *(uint4*)b0 = *(const uint4*)(vtb + (size_t)(2 * vjp) * 6144 + 1024 + vd);
            *(uint4*)b1 = *(const uint4*)(vtb + (size_t)(2 * vjp + 1) * 6144 + 1024 + vd);
            #pragma unroll
            for (int i = 0; i < 8; ++i) {
                const int off = swz(vd + i, vjp * 4);
                *(uint*)((char*)sVh + off) = (uint)a0[i] | ((uint)a1[i] << 16);
                *(uint*)((char*)sVl + off) = (uint)b0[i] | ((uint)b1[i] << 16);
            }
        }
        __syncthreads();

        // ---- QK^T: 4 j-tiles x 2 k-chunks x 3 split terms = 24 mfma
        f32x4 accS[4];
        #pragma unroll
        for (int t = 0; t < 4; ++t) accS[t] = (f32x4){0.f, 0.f, 0.f, 0.f};
        #pragma unroll
        for (int kc = 0; kc < 2; ++kc) {
            #pragma unroll
            for (int t = 0; t < 4; ++t) {
                const int off = swz(t * 16 + lr, (kc * 32 + lg * 8) * 2);
                short8 bhf = *(short8*)((char*)sKh + off);
                short8 blf = *(short8*)((char*)sKl + off);
                accS[t] = __builtin_amdgcn_mfma_f32_16x16x32_bf16(qh[kc], bhf, accS[t], 0, 0, 0);
                accS[t] = __builtin_amdgcn_mfma_f32_16x16x32_bf16(qh[kc], blf, accS[t], 0, 0, 0);
                accS[t] = __builtin_amdgcn_mfma_f32_16x16x32_bf16(ql[kc], bhf, accS[t], 0, 0, 0);
            }
        }

        // ---- online softmax (C-layout: row=lg*4+r, col j=t*16+lr)
        float p[4][4];
        float fac[4];
        #pragma unroll
        for (int r = 0; r < 4; ++r) {
            float v = fmaxf(fmaxf(accS[0][r], accS[1][r]), fmaxf(accS[2][r], accS[3][r]));
            v = fmaxf(v, __shfl_xor(v, 1));
            v = fmaxf(v, __shfl_xor(v, 2));
            v = fmaxf(v, __shfl_xor(v, 4));
            v = fmaxf(v, __shfl_xor(v, 8));
            const float mn = fmaxf(mrun[r], v);
            fac[r] = __expf(mrun[r] - mn);
            mrun[r] = mn;
            float rs = 0.f;
            #pragma unroll
            for (int t = 0; t < 4; ++t) {
                p[t][r] = __expf(accS[t][r] - mn);
                rs += p[t][r];
            }
            rs += __shfl_xor(rs, 1);
            rs += __shfl_xor(rs, 2);
            rs += __shfl_xor(rs, 4);
            rs += __shfl_xor(rs, 8);
            lrun[r] = lrun[r] * fac[r] + rs;
        }
        #pragma unroll
        for (int t = 0; t < 4; ++t)
            #pragma unroll
            for (int r = 0; r < 4; ++r) accO[t][r] *= fac[r];

        // ---- store P (split) to per-wave LDS
        #pragma unroll
        for (int t = 0; t < 4; ++t)
            #pragma unroll
            for (int r = 0; r < 4; ++r) {
                ushort hi, lo;
                split2(p[t][r], hi, lo);
                const int off = swz(lg * 4 + r, (t * 16 + lr) * 2);
                *(ushort*)((char*)Ph[wv] + off) = hi;
                *(ushort*)((char*)Pl[wv] + off) = lo;
            }

        // ---- PV: O += P * V
        #pragma unroll
        for (int jc = 0; jc < 2; ++jc) {
            const int aoff = swz(lr, (jc * 32 + lg * 8) * 2);
            short8 pah = *(short8*)((char*)Ph[wv] + aoff);
            short8 pal = *(short8*)((char*)Pl[wv] + aoff);
            #pragma unroll
            for (int dt = 0; dt < 4; ++dt) {
                const int boff = swz(dt * 16 + lr, (jc * 32 + lg * 8) * 2);
                short8 vhf = *(short8*)((char*)sVh + boff);
                short8 vlf = *(short8*)((char*)sVl + boff);
                accO[dt] = __builtin_amdgcn_mfma_f32_16x16x32_bf16(pah, vhf, accO[dt], 0, 0, 0);
                accO[dt] = __builtin_amdgcn_mfma_f32_16x16x32_bf16(pah, vlf, accO[dt], 0, 0, 0);
                accO[dt] = __builtin_amdgcn_mfma_f32_16x16x32_bf16(pal, vhf, accO[dt], 0, 0, 0);
            }
        }
    }

    // ---- normalize, split, write hi/lo
    #pragma unroll
    for (int r = 0; r < 4; ++r) {
        const float inv_l = 1.0f / lrun[r];
        const int q = q0 + wv * 16 + lg * 4 + r;
        const size_t ob = ((size_t)(b * S_ + q)) * INNER_ + h * 64;
        #pragma unroll
        for (int dt = 0; dt < 4; ++dt) {
            ushort hi, lo;
            split2(accO[dt][r] * inv_l, hi, lo);
            att_h[ob + dt * 16 + lr] = hi;
            att_l[ob + dt * 16 + lr] = lo;
        }
    }
}

// ---------------------------------------------------------------------------
// Launch
// ---------------------------------------------------------------------------
extern "C" void kernel_launch(void* const* d_in, const int* in_sizes, int n_in,
                              void* d_out, int out_size, void* d_ws, size_t ws_size,
                              hipStream_t stream) {
    const float* x        = (const float*)d_in[0];
    const float* w_qkv    = (const float*)d_in[1];
    const float* w_out    = (const float*)d_in[2];
    const float* b_out    = (const float*)d_in[3];
    const float* ln_gamma = (const float*)d_in[4];
    const float* ln_beta  = (const float*)d_in[5];
    float* out = (float*)d_out;

    char* wsb = (char*)d_ws;
    // [0, 96M): qkv fp32, rewritten in place to split-bf16 by rope_split
    float*  qkv   = (float*)wsb;
    // [96M, 128M): xn hi/lo (live until QKV gemm) overlaid by att hi/lo
    ushort* xn_h  = (ushort*)(wsb + 100663296);
    ushort* xn_l  = (ushort*)(wsb + 100663296 + 16777216);
    ushort* att_h = xn_h;
    ushort* att_l = xn_l;
    // [128M, 140M): w_qkv^T hi/lo overlaid by w_out^T hi/lo
    ushort* wqT_h = (ushort*)(wsb + 134217728);
    ushort* wqT_l = (ushort*)(wsb + 134217728 + 6291456);
    ushort* woT_h = wqT_h;
    ushort* woT_l = (ushort*)(wsb + 134217728 + 2097152);
    // [140M, 140.5M): rope tables
    float*  cost  = (float*)(wsb + 146800640);
    float*  sint  = cost + S_ * 32;

    // 1. LayerNorm -> split bf16
    ln_kernel<<<ROWS_, 256, 0, stream>>>(x, ln_gamma, ln_beta, xn_h, xn_l);

    // 2. w_qkv transpose+split
    wtrans_kernel<<<dim3(N3_ / 64, D_ / 64), 256, 0, stream>>>(w_qkv, wqT_h, wqT_l, D_, N3_);

    // 3. QKV projection (MFMA)
    gemm_split_kernel<<<dim3(N3_ / 128, ROWS_ / 128), 256, 0, stream>>>(
        xn_h, xn_l, wqT_h, wqT_l, qkv, ROWS_, N3_, D_, nullptr);

    // 4. RoPE table + fused rope/split (in place over qkv)
    rope_table_kernel<<<(S_ * 32) / 256, 256, 0, stream>>>(cost, sint);
    rope_split_kernel<<<ROWS_, 256, 0, stream>>>(qkv, cost, sint);

    // 5. Attention (v5: pre-split staging) -> split bf16 att
    attn_mfma_kernel<<<dim3(B_ * H_, S_ / 64), 256, 0, stream>>>(
        (const ushort*)qkv, att_h, att_l);

    // 6. w_out transpose+split
    wtrans_kernel<<<dim3(D_ / 64, D_ / 64), 256, 0, stream>>>(w_out, woT_h, woT_l, D_, D_);

    // 7. Output projection (MFMA) + bias -> d_out
    gemm_split_kernel<<<dim3(D_ / 128, ROWS_ / 128), 256, 0, stream>>>(
        att_h, att_l, woT_h, woT_l, out, ROWS_, D_, INNER_, b_out);
}

// Round 7
// 593.160 us; speedup vs baseline: 1.1439x; 1.1439x over previous
//
#include <hip/hip_runtime.h>
#include <hip/hip_bf16.h>
#include <math.h>

// Problem constants
#define B_ 4
#define S_ 2048
#define D_ 1024
#define H_ 16
#define DH_ 64
#define INNER_ 1024   // H_*DH_
#define N3_ 3072      // 3*INNER_
#define ROWS_ 8192    // B_*S_

typedef __attribute__((ext_vector_type(8))) short short8;
typedef __attribute__((ext_vector_type(4))) float f32x4;

// ---------------------------------------------------------------------------
// split fp32 -> bf16 hi + bf16 lo (hi+lo reproduces ~16 mantissa bits)
// ---------------------------------------------------------------------------
__device__ __forceinline__ void split2(float x, ushort& hi, ushort& lo) {
    __hip_bfloat16 h = __float2bfloat16(x);
    float hf = __bfloat162float(h);
    __hip_bfloat16 l = __float2bfloat16(x - hf);
    hi = *reinterpret_cast<ushort*>(&h);
    lo = *reinterpret_cast<ushort*>(&l);
}

// XOR-swizzled byte offset into a row-major [.][64] bf16 tile (128B rows).
__device__ __forceinline__ int swz(int row, int colByte) {
    return row * 128 + (colByte ^ ((row & 7) << 4));
}

// ---------------------------------------------------------------------------
// LayerNorm: one block (256 threads) per row of 1024 floats -> split bf16.
// ---------------------------------------------------------------------------
__global__ __launch_bounds__(256) void ln_kernel(const float* __restrict__ x,
                                                 const float* __restrict__ gamma,
                                                 const float* __restrict__ beta,
                                                 ushort* __restrict__ xn_h,
                                                 ushort* __restrict__ xn_l) {
    const int row = blockIdx.x;
    const int tid = threadIdx.x;
    const float4 v = ((const float4*)(x + (size_t)row * D_))[tid];
    float s  = v.x + v.y + v.z + v.w;
    float ss = v.x * v.x + v.y * v.y + v.z * v.z + v.w * v.w;
    #pragma unroll
    for (int off = 32; off > 0; off >>= 1) {
        s  += __shfl_down(s, off);
        ss += __shfl_down(ss, off);
    }
    __shared__ float red[8];
    const int wave = tid >> 6, lane = tid & 63;
    if (lane == 0) { red[wave] = s; red[4 + wave] = ss; }
    __syncthreads();
    const float S  = red[0] + red[1] + red[2] + red[3];
    const float SS = red[4] + red[5] + red[6] + red[7];
    const float mu  = S * (1.0f / D_);
    const float var = SS * (1.0f / D_) - mu * mu;
    const float rs  = rsqrtf(var + 1e-5f);
    const float4 g  = ((const float4*)gamma)[tid];
    const float4 bb = ((const float4*)beta)[tid];
    float o0 = (v.x - mu) * rs * g.x + bb.x;
    float o1 = (v.y - mu) * rs * g.y + bb.y;
    float o2 = (v.z - mu) * rs * g.z + bb.z;
    float o3 = (v.w - mu) * rs * g.w + bb.w;
    ushort h0, l0, h1, l1, h2, l2, h3, l3;
    split2(o0, h0, l0); split2(o1, h1, l1);
    split2(o2, h2, l2); split2(o3, h3, l3);
    *(ushort4*)(xn_h + (size_t)row * D_ + tid * 4) = make_ushort4(h0, h1, h2, h3);
    *(ushort4*)(xn_l + (size_t)row * D_ + tid * 4) = make_ushort4(l0, l1, l2, l3);
}

// ---------------------------------------------------------------------------
// Weight transpose+split: W [K][N] fp32 -> Th/Tl [N][K] bf16.
// ---------------------------------------------------------------------------
__global__ __launch_bounds__(256) void wtrans_kernel(const float* __restrict__ W,
                                                     ushort* __restrict__ Th,
                                                     ushort* __restrict__ Tl,
                                                     int K, int N) {
    __shared__ float tile[64][68];
    const int tid = threadIdx.x;
    const int n0 = blockIdx.x * 64, k0 = blockIdx.y * 64;
    const int kr = tid >> 4, nc = (tid & 15) * 4;
    #pragma unroll
    for (int li = 0; li < 4; ++li) {
        const int k = kr + li * 16;
        *(float4*)&tile[k][nc] = *(const float4*)(W + (size_t)(k0 + k) * N + n0 + nc);
    }
    __syncthreads();
    const int nl = tid >> 2;
    const int ks = (tid & 3) * 16;
    ushort hbuf[16], lbuf[16];
    #pragma unroll
    for (int i = 0; i < 16; ++i) split2(tile[ks + i][nl], hbuf[i], lbuf[i]);
    ushort* th = Th + (size_t)(n0 + nl) * K + k0 + ks;
    ushort* tl = Tl + (size_t)(n0 + nl) * K + k0 + ks;
    #pragma unroll
    for (int i = 0; i < 4; ++i) {
        *(ushort4*)(th + i * 4) = make_ushort4(hbuf[i*4], hbuf[i*4+1], hbuf[i*4+2], hbuf[i*4+3]);
        *(ushort4*)(tl + i * 4) = make_ushort4(lbuf[i*4], lbuf[i*4+1], lbuf[i*4+2], lbuf[i*4+3]);
    }
}

// ---------------------------------------------------------------------------
// Split-bf16 MFMA GEMM: C[M,N] = (Ah+Al)[M,K] @ (Bh+Bl)^T[N,K]  (+ bias)
// ---------------------------------------------------------------------------
__global__ __launch_bounds__(256) void gemm_split_kernel(
        const ushort* __restrict__ Ah, const ushort* __restrict__ Al,
        const ushort* __restrict__ Bh, const ushort* __restrict__ Bl,
        float* __restrict__ C, int M, int N, int K,
        const float* __restrict__ bias) {
    __shared__ __align__(16) ushort As_h[128 * 64], As_l[128 * 64];
    __shared__ __align__(16) ushort Bs_h[128 * 64], Bs_l[128 * 64];
    const int tid  = threadIdx.x;
    const int lane = tid & 63;
    const int wv   = tid >> 6;
    const int lr = lane & 15, lg = lane >> 4;
    const int wr = wv >> 1, wc = wv & 1;
    const int m0 = blockIdx.y * 128, n0 = blockIdx.x * 128;

    f32x4 acc[4][4];
    #pragma unroll
    for (int i = 0; i < 4; ++i)
        #pragma unroll
        for (int j = 0; j < 4; ++j) acc[i][j] = (f32x4){0.f, 0.f, 0.f, 0.f};

    const int sr = tid >> 3;
    const int ss = (tid & 7) * 16;

    for (int k0 = 0; k0 < K; k0 += 64) {
        __syncthreads();
        #pragma unroll
        for (int li = 0; li < 4; ++li) {
            const int r = sr + li * 32;
            const size_t ga = (size_t)(m0 + r) * K + k0 + (ss >> 1);
            const size_t gb = (size_t)(n0 + r) * K + k0 + (ss >> 1);
            const int off = swz(r, ss);
            *(uint4*)((char*)As_h + off) = *(const uint4*)(Ah + ga);
            *(uint4*)((char*)As_l + off) = *(const uint4*)(Al + ga);
            *(uint4*)((char*)Bs_h + off) = *(const uint4*)(Bh + gb);
            *(uint4*)((char*)Bs_l + off) = *(const uint4*)(Bl + gb);
        }
        __syncthreads();
        #pragma unroll
        for (int kc = 0; kc < 2; ++kc) {
            const int cb = kc * 64 + lg * 16;
            short8 ah[4], al[4], bhf[4], blf[4];
            #pragma unroll
            for (int i = 0; i < 4; ++i) {
                const int ra = wr * 64 + i * 16 + lr;
                const int rb = wc * 64 + i * 16 + lr;
                ah[i]  = *(short8*)((char*)As_h + swz(ra, cb));
                al[i]  = *(short8*)((char*)As_l + swz(ra, cb));
                bhf[i] = *(short8*)((char*)Bs_h + swz(rb, cb));
                blf[i] = *(short8*)((char*)Bs_l + swz(rb, cb));
            }
            #pragma unroll
            for (int mi = 0; mi < 4; ++mi)
                #pragma unroll
                for (int ni = 0; ni < 4; ++ni) {
                    acc[mi][ni] = __builtin_amdgcn_mfma_f32_16x16x32_bf16(ah[mi], bhf[ni], acc[mi][ni], 0, 0, 0);
                    acc[mi][ni] = __builtin_amdgcn_mfma_f32_16x16x32_bf16(ah[mi], blf[ni], acc[mi][ni], 0, 0, 0);
                    acc[mi][ni] = __builtin_amdgcn_mfma_f32_16x16x32_bf16(al[mi], bhf[ni], acc[mi][ni], 0, 0, 0);
                }
        }
    }

    #pragma unroll
    for (int mi = 0; mi < 4; ++mi) {
        #pragma unroll
        for (int rr = 0; rr < 4; ++rr) {
            const int row = m0 + wr * 64 + mi * 16 + lg * 4 + rr;
            float* crow = C + (size_t)row * N + n0 + wc * 64;
            #pragma unroll
            for (int ni = 0; ni < 4; ++ni) {
                const int col = ni * 16 + lr;
                float v = acc[mi][ni][rr];
                if (bias) v += bias[n0 + wc * 64 + col];
                crow[col] = v;
            }
        }
    }
}

// ---------------------------------------------------------------------------
// RoPE cos/sin table: [S_][32] each.
// ---------------------------------------------------------------------------
__global__ __launch_bounds__(256) void rope_table_kernel(float* __restrict__ cost,
                                                         float* __restrict__ sint) {
    const int idx = blockIdx.x * 256 + threadIdx.x;
    const int s = idx >> 5;
    const int i = idx & 31;
    const float inv = powf(10000.0f, -(2.0f * (float)i) / 64.0f);
    const float f = (float)s * inv;
    float sv, cv;
    sincosf(f, &sv, &cv);
    cost[idx] = cv;
    sint[idx] = sv;
}

// ---------------------------------------------------------------------------
// RoPE + split, IN PLACE over the qkv fp32 buffer.  One block per row.
// Row layout after (ushort units, row base = row*6144):
//   [0,1024) Qh (pre-scaled 1/8)  [1024,2048) Ql
//   [2048,3072) Kh                [3072,4096) Kl
//   [4096,5120) Vh                [5120,6144) Vl
// ---------------------------------------------------------------------------
__global__ __launch_bounds__(256) void rope_split_kernel(float* __restrict__ qkv,
                                                         const float* __restrict__ cost,
                                                         const float* __restrict__ sint) {
    __shared__ float qs[1024], ks[1024], vs[1024];
    __shared__ ushort qhs[1024], qls[1024], khs[1024], kls[1024], vhs[1024], vls[1024];
    const int row = blockIdx.x;
    const int spos = row & (S_ - 1);
    const int tid = threadIdx.x;
    float* base = qkv + (size_t)row * N3_;
    ((float4*)qs)[tid] = ((const float4*)(base))[tid];
    ((float4*)ks)[tid] = ((const float4*)(base + 1024))[tid];
    ((float4*)vs)[tid] = ((const float4*)(base + 2048))[tid];
    __syncthreads();
    #pragma unroll
    for (int pp = 0; pp < 2; ++pp) {
        const int p = tid + pp * 256;
        const int h = p >> 5, d = p & 31;
        const float c  = cost[spos * 32 + d];
        const float sn = sint[spos * 32 + d];
        const int c1 = h * 64 + d, c2 = c1 + 32;
        const float q1 = qs[c1], q2 = qs[c2];
        const float k1 = ks[c1], k2 = ks[c2];
        ushort hh, ll;
        split2((q1 * c - q2 * sn) * 0.125f, hh, ll); qhs[c1] = hh; qls[c1] = ll;
        split2((q1 * sn + q2 * c) * 0.125f, hh, ll); qhs[c2] = hh; qls[c2] = ll;
        split2(k1 * c - k2 * sn, hh, ll);            khs[c1] = hh; kls[c1] = ll;
        split2(k1 * sn + k2 * c, hh, ll);            khs[c2] = hh; kls[c2] = ll;
        split2(vs[c1], hh, ll);                      vhs[c1] = hh; vls[c1] = ll;
        split2(vs[c2], hh, ll);                      vhs[c2] = hh; vls[c2] = ll;
    }
    __syncthreads();
    ushort* W = (ushort*)base;
    *(ushort4*)(W + tid * 4)        = *(ushort4*)(qhs + tid * 4);
    *(ushort4*)(W + 1024 + tid * 4) = *(ushort4*)(qls + tid * 4);
    *(ushort4*)(W + 2048 + tid * 4) = *(ushort4*)(khs + tid * 4);
    *(ushort4*)(W + 3072 + tid * 4) = *(ushort4*)(kls + tid * 4);
    *(ushort4*)(W + 4096 + tid * 4) = *(ushort4*)(vhs + tid * 4);
    *(ushort4*)(W + 5120 + tid * 4) = *(ushort4*)(vls + tid * 4);
}

// ---------------------------------------------------------------------------
// Flash attention v6: split-bf16 MFMA, 32 q-rows/wave (2 row-tiles),
// T14 async staging (issue global loads early, LDS-write late), per-lane
// deferred l-sum.  Block = 4 waves = 128 q-rows; grid (B*H, S/128).
// ---------------------------------------------------------------------------
__global__ __launch_bounds__(256) void attn_mfma_kernel(const ushort* __restrict__ Q16,
                                                        ushort* __restrict__ att_h,
                                                        ushort* __restrict__ att_l) {
    __shared__ __align__(16) ushort sKh[64 * 64], sKl[64 * 64];
    __shared__ __align__(16) ushort sVh[64 * 64], sVl[64 * 64];
    __shared__ __align__(16) ushort Ph[4][16 * 64], Pl[4][16 * 64];

    const int tid  = threadIdx.x;
    const int lane = tid & 63;
    const int wv   = tid >> 6;
    const int lr   = lane & 15;
    const int lg   = lane >> 4;

    const int bh = blockIdx.x;
    const int b  = bh >> 4;
    const int h  = bh & 15;
    const int q0 = blockIdx.y * 128;

    // ---- Q fragments (2 row-tiles per wave), pre-split/pre-scaled
    short8 qh[2][2], ql[2][2];
    #pragma unroll
    for (int qt = 0; qt < 2; ++qt) {
        const int qrow = q0 + wv * 32 + qt * 16 + lr;
        const ushort* qp = Q16 + (size_t)(b * S_ + qrow) * 6144 + h * 64;
        #pragma unroll
        for (int kc = 0; kc < 2; ++kc) {
            qh[qt][kc] = *(const short8*)(qp + kc * 32 + lg * 8);
            ql[qt][kc] = *(const short8*)(qp + 1024 + kc * 32 + lg * 8);
        }
    }

    f32x4 accO[2][4];
    #pragma unroll
    for (int qt = 0; qt < 2; ++qt)
        #pragma unroll
        for (int t = 0; t < 4; ++t) accO[qt][t] = (f32x4){0.f, 0.f, 0.f, 0.f};
    float mrun[2][4], lrun[2][4];
    #pragma unroll
    for (int qt = 0; qt < 2; ++qt)
        #pragma unroll
        for (int r = 0; r < 4; ++r) { mrun[qt][r] = -1e30f; lrun[qt][r] = 0.f; }

    // staging indices
    const int kr0 = tid >> 3, ksl = tid & 7;      // K: row, 16B slot
    const int vjp = tid & 31;                     // V: j-pair 0..31
    const int vd  = (tid >> 5) * 8;               // V: d base

    const ushort* kvbase = Q16 + (size_t)(b * S_) * 6144 + h * 64;

    // staging registers (tile t+1 in flight)
    short8 rkh0, rkh1, rkl0, rkl1, rv0h, rv1h, rv0l, rv1l;

#define LOADT(J0)                                                              \
    {                                                                          \
        const ushort* ktb = kvbase + (size_t)(J0) * 6144 + 2048;               \
        rkh0 = *(const short8*)(ktb + (size_t)kr0 * 6144 + ksl * 8);           \
        rkl0 = *(const short8*)(ktb + (size_t)kr0 * 6144 + 1024 + ksl * 8);    \
        rkh1 = *(const short8*)(ktb + (size_t)(kr0 + 32) * 6144 + ksl * 8);    \
        rkl1 = *(const short8*)(ktb + (size_t)(kr0 + 32) * 6144 + 1024 + ksl * 8); \
        const ushort* vtb = kvbase + (size_t)(J0) * 6144 + 4096;               \
        rv0h = *(const short8*)(vtb + (size_t)(2 * vjp) * 6144 + vd);          \
        rv1h = *(const short8*)(vtb + (size_t)(2 * vjp + 1) * 6144 + vd);      \
        rv0l = *(const short8*)(vtb + (size_t)(2 * vjp) * 6144 + 1024 + vd);   \
        rv1l = *(const short8*)(vtb + (size_t)(2 * vjp + 1) * 6144 + 1024 + vd); \
    }

#define WRITET()                                                               \
    {                                                                          \
        const int offa = swz(kr0, ksl * 16);                                   \
        const int offb = swz(kr0 + 32, ksl * 16);                              \
        *(short8*)((char*)sKh + offa) = rkh0;                                  \
        *(short8*)((char*)sKl + offa) = rkl0;                                  \
        *(short8*)((char*)sKh + offb) = rkh1;                                  \
        *(short8*)((char*)sKl + offb) = rkl1;                                  \
        _Pragma("unroll")                                                      \
        for (int i = 0; i < 8; ++i) {                                          \
            const int off = swz(vd + i, vjp * 4);                              \
            *(uint*)((char*)sVh + off) = (uint)(ushort)rv0h[i] | ((uint)(ushort)rv1h[i] << 16); \
            *(uint*)((char*)sVl + off) = (uint)(ushort)rv0l[i] | ((uint)(ushort)rv1l[i] << 16); \
        }                                                                      \
    }

    LOADT(0)
    WRITET()

    const int NT = S_ / 64;
    for (int t = 0; t < NT; ++t) {
        __syncthreads();   // LDS tile t ready
        if (t + 1 < NT) LOADT((t + 1) * 64)   // issue next-tile loads (latency hidden)

        // ---- QK^T for both row-tiles: 4 j-tiles x 2 kc x 3 terms x 2 qt
        f32x4 accS[2][4];
        #pragma unroll
        for (int qt = 0; qt < 2; ++qt)
            #pragma unroll
            for (int tt = 0; tt < 4; ++tt) accS[qt][tt] = (f32x4){0.f, 0.f, 0.f, 0.f};
        #pragma unroll
        for (int kc = 0; kc < 2; ++kc) {
            #pragma unroll
            for (int tt = 0; tt < 4; ++tt) {
                const int off = swz(tt * 16 + lr, (kc * 32 + lg * 8) * 2);
                short8 bhf = *(short8*)((char*)sKh + off);
                short8 blf = *(short8*)((char*)sKl + off);
                #pragma unroll
                for (int qt = 0; qt < 2; ++qt) {
                    accS[qt][tt] = __builtin_amdgcn_mfma_f32_16x16x32_bf16(qh[qt][kc], bhf, accS[qt][tt], 0, 0, 0);
                    accS[qt][tt] = __builtin_amdgcn_mfma_f32_16x16x32_bf16(qh[qt][kc], blf, accS[qt][tt], 0, 0, 0);
                    accS[qt][tt] = __builtin_amdgcn_mfma_f32_16x16x32_bf16(ql[qt][kc], bhf, accS[qt][tt], 0, 0, 0);
                }
            }
        }

        // ---- per row-tile: softmax, P store, PV
        #pragma unroll
        for (int qt = 0; qt < 2; ++qt) {
            float p[4][4];
            float fac[4];
            #pragma unroll
            for (int r = 0; r < 4; ++r) {
                float v = fmaxf(fmaxf(accS[qt][0][r], accS[qt][1][r]),
                                fmaxf(accS[qt][2][r], accS[qt][3][r]));
                v = fmaxf(v, __shfl_xor(v, 1));
                v = fmaxf(v, __shfl_xor(v, 2));
                v = fmaxf(v, __shfl_xor(v, 4));
                v = fmaxf(v, __shfl_xor(v, 8));
                const float mn = fmaxf(mrun[qt][r], v);
                fac[r] = __expf(mrun[qt][r] - mn);
                mrun[qt][r] = mn;
                float ps = 0.f;
                #pragma unroll
                for (int tt = 0; tt < 4; ++tt) {
                    p[tt][r] = __expf(accS[qt][tt][r] - mn);
                    ps += p[tt][r];
                }
                lrun[qt][r] = lrun[qt][r] * fac[r] + ps;   // per-lane partial
            }
            #pragma unroll
            for (int tt = 0; tt < 4; ++tt)
                #pragma unroll
                for (int r = 0; r < 4; ++r) accO[qt][tt][r] *= fac[r];

            // store P (split) to per-wave LDS
            #pragma unroll
            for (int tt = 0; tt < 4; ++tt)
                #pragma unroll
                for (int r = 0; r < 4; ++r) {
                    ushort hi, lo;
                    split2(p[tt][r], hi, lo);
                    const int off = swz(lg * 4 + r, (tt * 16 + lr) * 2);
                    *(ushort*)((char*)Ph[wv] + off) = hi;
                    *(ushort*)((char*)Pl[wv] + off) = lo;
                }

            // PV: O += P * V
            #pragma unroll
            for (int jc = 0; jc < 2; ++jc) {
                const int aoff = swz(lr, (jc * 32 + lg * 8) * 2);
                short8 pah = *(short8*)((char*)Ph[wv] + aoff);
                short8 pal = *(short8*)((char*)Pl[wv] + aoff);
                #pragma unroll
                for (int dt = 0; dt < 4; ++dt) {
                    const int boff = swz(dt * 16 + lr, (jc * 32 + lg * 8) * 2);
                    short8 vhf = *(short8*)((char*)sVh + boff);
                    short8 vlf = *(short8*)((char*)sVl + boff);
                    accO[qt][dt] = __builtin_amdgcn_mfma_f32_16x16x32_bf16(pah, vhf, accO[qt][dt], 0, 0, 0);
                    accO[qt][dt] = __builtin_amdgcn_mfma_f32_16x16x32_bf16(pah, vlf, accO[qt][dt], 0, 0, 0);
                    accO[qt][dt] = __builtin_amdgcn_mfma_f32_16x16x32_bf16(pal, vhf, accO[qt][dt], 0, 0, 0);
                }
            }
        }

        __syncthreads();   // all waves done reading K/V LDS
        if (t + 1 < NT) WRITET()
    }

    // ---- final cross-lane l reduction, normalize, split, write hi/lo
    #pragma unroll
    for (int qt = 0; qt < 2; ++qt) {
        #pragma unroll
        for (int r = 0; r < 4; ++r) {
            float L = lrun[qt][r];
            L += __shfl_xor(L, 1);
            L += __shfl_xor(L, 2);
            L += __shfl_xor(L, 4);
            L += __shfl_xor(L, 8);
            const float inv_l = 1.0f / L;
            const int q = q0 + wv * 32 + qt * 16 + lg * 4 + r;
            const size_t ob = ((size_t)(b * S_ + q)) * INNER_ + h * 64;
            #pragma unroll
            for (int dt = 0; dt < 4; ++dt) {
                ushort hi, lo;
                split2(accO[qt][dt][r] * inv_l, hi, lo);
                att_h[ob + dt * 16 + lr] = hi;
                att_l[ob + dt * 16 + lr] = lo;
            }
        }
    }
#undef LOADT
#undef WRITET
}

// ---------------------------------------------------------------------------
// Launch
// ---------------------------------------------------------------------------
extern "C" void kernel_launch(void* const* d_in, const int* in_sizes, int n_in,
                              void* d_out, int out_size, void* d_ws, size_t ws_size,
                              hipStream_t stream) {
    const float* x        = (const float*)d_in[0];
    const float* w_qkv    = (const float*)d_in[1];
    const float* w_out    = (const float*)d_in[2];
    const float* b_out    = (const float*)d_in[3];
    const float* ln_gamma = (const float*)d_in[4];
    const float* ln_beta  = (const float*)d_in[5];
    float* out = (float*)d_out;

    char* wsb = (char*)d_ws;
    float*  qkv   = (float*)wsb;                                  // [0,96M) fp32 -> split in place
    ushort* xn_h  = (ushort*)(wsb + 100663296);                   // [96M,128M)
    ushort* xn_l  = (ushort*)(wsb + 100663296 + 16777216);
    ushort* att_h = xn_h;
    ushort* att_l = xn_l;
    ushort* wqT_h = (ushort*)(wsb + 134217728);                   // [128M,140M)
    ushort* wqT_l = (ushort*)(wsb + 134217728 + 6291456);
    ushort* woT_h = wqT_h;
    ushort* woT_l = (ushort*)(wsb + 134217728 + 2097152);
    float*  cost  = (float*)(wsb + 146800640);                    // [140M,140.5M)
    float*  sint  = cost + S_ * 32;

    // 1. LayerNorm -> split bf16
    ln_kernel<<<ROWS_, 256, 0, stream>>>(x, ln_gamma, ln_beta, xn_h, xn_l);

    // 2. w_qkv transpose+split
    wtrans_kernel<<<dim3(N3_ / 64, D_ / 64), 256, 0, stream>>>(w_qkv, wqT_h, wqT_l, D_, N3_);

    // 3. QKV projection (MFMA)
    gemm_split_kernel<<<dim3(N3_ / 128, ROWS_ / 128), 256, 0, stream>>>(
        xn_h, xn_l, wqT_h, wqT_l, qkv, ROWS_, N3_, D_, nullptr);

    // 4. RoPE table + fused rope/split (in place over qkv)
    rope_table_kernel<<<(S_ * 32) / 256, 256, 0, stream>>>(cost, sint);
    rope_split_kernel<<<ROWS_, 256, 0, stream>>>(qkv, cost, sint);

    // 5. Attention (v6: 2 row-tiles/wave + T14 async staging)
    attn_mfma_kernel<<<dim3(B_ * H_, S_ / 128), 256, 0, stream>>>(
        (const ushort*)qkv, att_h, att_l);

    // 6. w_out transpose+split
    wtrans_kernel<<<dim3(D_ / 64, D_ / 64), 256, 0, stream>>>(w_out, woT_h, woT_l, D_, D_);

    // 7. Output projection (MFMA) + bias -> d_out
    gemm_split_kernel<<<dim3(D_ / 128, ROWS_ / 128), 256, 0, stream>>>(
        att_h, att_l, woT_h, woT_l, out, ROWS_, D_, INNER_, b_out);
}